// Round 6
// baseline (12306.453 us; speedup 1.0000x reference)
//
#include <hip/hip_runtime.h>

#define SEQL 256
#define BATCH 64
#define HID 1024
#define NLAY 5
#define NCLS 32000
#define RING_R 32   // ring depth (steps) for layer 0..2 outputs
#define R4 8        // ring depth for layer-4 output exchange

typedef __attribute__((__ext_vector_type__(8))) short s16x8;
typedef __attribute__((__ext_vector_type__(4))) float f32x4;

__device__ __forceinline__ unsigned short f2bf(float f) {
  unsigned u = __float_as_uint(f);
  u = u + 0x7fffu + ((u >> 16) & 1u);
  return (unsigned short)(u >> 16);
}
__device__ __forceinline__ float bf2f(unsigned short s) {
  return __uint_as_float(((unsigned)s) << 16);
}
__device__ __forceinline__ float sigm(float x) { return 1.f / (1.f + __expf(-x)); }
__device__ __forceinline__ float tanh_f(float x) {
  float a = fabsf(x);
  float e = __expf(-2.f * a);
  float t = (1.f - e) / (1.f + e);
  return x < 0.f ? -t : t;
}

__device__ __forceinline__ void llds16(const void* g, void* l) {
  __builtin_amdgcn_global_load_lds((const __attribute__((address_space(1))) unsigned int*)g,
                                   (__attribute__((address_space(3))) unsigned int*)l,
                                   16, 0, 0);
}

#define AFENCE asm volatile("" ::: "memory")
#define VW0 asm volatile("s_waitcnt vmcnt(0)" ::: "memory")
#define LW0 asm volatile("s_waitcnt lgkmcnt(0)" ::: "memory")
#define SBAR __builtin_amdgcn_s_barrier()

// ---------------- weight packing: fp32 Wx/Wh -> bf16 MFMA-B fragments ----------------
// Wp index: ((((l*64 + j)*4 + g)*64 + k0)*64 + lane)*8 + i   (bf16 units)
// lane element i: k = k0*32 + (lane>>4)*8 + i, col h = j*16 + (lane&15)
// rows k<1024 from Wx[l][g], rows >=1024 from Wh[l][g].
__global__ void pack_k(const float* __restrict__ Wx, const float* __restrict__ Wh,
                       unsigned short* __restrict__ Wp) {
  int bid = blockIdx.x;
  int k0 = bid & 63;
  int g = (bid >> 6) & 3;
  int j = (bid >> 8) & 63;
  int l = bid >> 14;
  int lane = threadIdx.x;
  int h = j * 16 + (lane & 15);
  int kb = k0 * 32 + (lane >> 4) * 8;
  const float* src;
  if (kb < 1024) src = Wx + ((size_t)((l * 4 + g) * 1024 + kb)) * 1024 + h;
  else           src = Wh + ((size_t)((l * 4 + g) * 1024 + (kb - 1024))) * 1024 + h;
  unsigned short o[8];
#pragma unroll
  for (int i = 0; i < 8; ++i) o[i] = f2bf(src[(size_t)i * 1024]);
  uint4 v;
  v.x = (unsigned)o[0] | ((unsigned)o[1] << 16);
  v.y = (unsigned)o[2] | ((unsigned)o[3] << 16);
  v.z = (unsigned)o[4] | ((unsigned)o[5] << 16);
  v.w = (unsigned)o[6] | ((unsigned)o[7] << 16);
  *(uint4*)(Wp + (((size_t)bid * 64 + lane) * 8)) = v;
}

// ---------------- embedding gather -> x0 ----------------
__global__ void embed_k(const int* __restrict__ X, const float* __restrict__ emb,
                        unsigned short* __restrict__ x0) {
  int sb = blockIdx.x;  // t*64 + b
  int t = sb >> 6, b = sb & 63;
  int row = X[b * SEQL + t];
  float4 v = ((const float4*)(emb + (size_t)row * HID))[threadIdx.x];
  unsigned short o0 = f2bf(v.x), o1 = f2bf(v.y), o2 = f2bf(v.z), o3 = f2bf(v.w);
  uint2 pk;
  pk.x = (unsigned)o0 | ((unsigned)o1 << 16);
  pk.y = (unsigned)o2 | ((unsigned)o3 << 16);
  ((uint2*)(x0 + (size_t)sb * HID))[threadIdx.x] = pk;
}

extern __shared__ char smem[];

// ==================== PASS A: 4-layer wavefront ====================
// 256 blocks = 4 layers x 64 col-groups; block owns 16 cols x 4 gates, full
// batch (64 rows). Wave w: gate g = w&3, K-half kh = w>>2; weights 32 s16x8
// (128 VGPR) per wave. One 128KB LDS A-buffer time-shared x-half / h-half.
// Layer l at wavefront step s computes t = s - l. Exchange: sc1 stores into
// per-layer rings (R=32) / hs3 full buffer; flag[l*64+cg] = completed steps.
// Poll: own layer >= t, upstream >= t+1, downstream >= t-31 (ring WAR).

__device__ __forceinline__ void stageAB(const char* slab, char* AB, int tid) {
#pragma unroll
  for (int it = 0; it < 16; ++it) {
    int c = tid + it * 512;
    int row = c >> 7, slot = c & 127;
    llds16(slab + row * 2048 + ((slot ^ (row & 7)) << 4), AB + row * 2048 + slot * 16);
  }
}

__device__ __forceinline__ void mfma128(const char* AB, const s16x8* wreg, int hl,
                                        int ksub, f32x4 (&acc)[4]) {
  const int sw = hl & 7;
#pragma unroll
  for (int i = 0; i < 32; ++i) {
    int so = ((i * 4 + ksub) ^ sw) << 4;
#pragma unroll
    for (int m = 0; m < 4; ++m) {
      s16x8 a = *(const s16x8*)(AB + (m * 16 + hl) * 2048 + so);
      acc[m] = __builtin_amdgcn_mfma_f32_16x16x32_bf16(a, wreg[i], acc[m], 0, 0, 0);
    }
  }
}

__device__ __forceinline__ void pollA(const int* fl, int l, int t, int lane) {
  for (;;) {
    bool ok = true;
    int own = __hip_atomic_load(&fl[(l * 64 + lane) * 4], __ATOMIC_RELAXED, __HIP_MEMORY_SCOPE_AGENT);
    ok &= (own >= t);
    if (l > 0) {
      int up = __hip_atomic_load(&fl[((l - 1) * 64 + lane) * 4], __ATOMIC_RELAXED, __HIP_MEMORY_SCOPE_AGENT);
      ok &= (up >= t + 1);
    }
    if (l < 3) {
      int dn = __hip_atomic_load(&fl[((l + 1) * 64 + lane) * 4], __ATOMIC_RELAXED, __HIP_MEMORY_SCOPE_AGENT);
      ok &= (dn >= t - (RING_R - 1));
    }
    if (__all(ok)) break;
    __builtin_amdgcn_s_sleep(1);
  }
}

__global__ void __launch_bounds__(512) __attribute__((amdgpu_waves_per_eu(2, 2)))
lstm_wave(const unsigned short* __restrict__ Wp, const float* __restrict__ bias,
          const unsigned short* __restrict__ x0, unsigned short* ring,
          unsigned short* hs3, int* flags) {
  const int l = blockIdx.x >> 6;   // layer 0..3
  const int cg = blockIdx.x & 63;  // col group
  const int tid = threadIdx.x;
  const int wave = tid >> 6;
  const int lane = tid & 63;
  const int g = wave & 3;
  const int kh = wave >> 2;
  const int hl = lane & 15;
  const int ksub = lane >> 4;
  char* AB = smem;                       // 131072
  float* pre = (float*)(smem + 131072);  // [4][64][17] f32 = 17408

  const unsigned short* wpL =
      Wp + (size_t)(l * 64 + cg) * 131072 + (size_t)g * 32768 + (size_t)kh * 16384;
  const float biasv = bias[(l * 4 + g) * 1024 + cg * 16 + hl];

  s16x8 wreg[32];
#pragma unroll
  for (int i = 0; i < 32; ++i) wreg[i] = *(const s16x8*)(wpL + i * 512 + lane * 8);

  float c0 = 0.f, c1 = 0.f;  // cell state: thread -> (b = tid>>3, cols gh, gh+1)
  const int gb = tid >> 3;
  const int gh = (tid & 7) * 2;

  for (int t = 0; t < SEQL; ++t) {
    // P0: poll dependencies (wave 0 only)
    if (wave == 0) pollA(flags, l, t, lane);
    AFENCE; SBAR;

    // P1: stage x_t (layer 0: embedded input; else upstream ring slot t%R)
    const char* xs = (l == 0)
        ? (const char*)x0 + (size_t)t * 131072
        : (const char*)ring + ((size_t)((l - 1) * RING_R + (t & (RING_R - 1)))) * 131072;
    stageAB(xs, AB, tid);
    VW0; SBAR;

    // P2: x-half MFMA (kh==0 waves) -> pre = acc + bias
    f32x4 acc[4];
#pragma unroll
    for (int m = 0; m < 4; ++m) acc[m] = (f32x4){0.f, 0.f, 0.f, 0.f};
    if (kh == 0) {
      mfma128(AB, wreg, hl, ksub, acc);
#pragma unroll
      for (int m = 0; m < 4; ++m)
#pragma unroll
        for (int r = 0; r < 4; ++r)
          pre[(g * 64 + m * 16 + ksub * 4 + r) * 17 + hl] = acc[m][r] + biasv;
    }
    LW0; SBAR;

    // P3: stage h_{t-1} (own layer ring / hs3)
    if (t > 0) {
      const char* hsrc = (l == 3)
          ? (const char*)hs3 + (size_t)(t - 1) * 131072
          : (const char*)ring + ((size_t)(l * RING_R + ((t - 1) & (RING_R - 1)))) * 131072;
      stageAB(hsrc, AB, tid);
    }
    VW0; SBAR;

    // P4: h-half MFMA (kh==1 waves) -> pre += acc
    if (kh == 1 && t > 0) {
      mfma128(AB, wreg, hl, ksub, acc);
#pragma unroll
      for (int m = 0; m < 4; ++m)
#pragma unroll
        for (int r = 0; r < 4; ++r)
          pre[(g * 64 + m * 16 + ksub * 4 + r) * 17 + hl] += acc[m][r];
    }
    LW0; SBAR;

    // P5: gates (512 threads x 2 cells), sc1 h-store
    {
      unsigned short hw[2];
#pragma unroll
      for (int q = 0; q < 2; ++q) {
        int hh = gh + q;
        float pi = pre[(0 * 64 + gb) * 17 + hh];
        float pf = pre[(1 * 64 + gb) * 17 + hh];
        float po = pre[(2 * 64 + gb) * 17 + hh];
        float pg = pre[(3 * 64 + gb) * 17 + hh];
        float iv = sigm(pi), fv = sigm(pf), ov = sigm(po), gv = tanh_f(pg);
        float cprev = q ? c1 : c0;
        float c = fv * cprev + iv * gv;
        if (q) c1 = c; else c0 = c;
        hw[q] = f2bf(ov * tanh_f(c));
      }
      unsigned pk = (unsigned)hw[0] | ((unsigned)hw[1] << 16);
      unsigned short* dstbase = (l == 3)
          ? hs3 + (size_t)t * 65536
          : ring + ((size_t)(l * RING_R + (t & (RING_R - 1)))) * 65536;
      unsigned* dst = (unsigned*)(dstbase + (size_t)gb * 1024 + cg * 16 + gh);
      __hip_atomic_store(dst, pk, __ATOMIC_RELAXED, __HIP_MEMORY_SCOPE_AGENT);
    }
    VW0;   // own h stores acked at coherence point
    SBAR;  // all waves' stores visible
    if (tid == 0)
      __hip_atomic_store(&flags[(l * 64 + cg) * 4], t + 1, __ATOMIC_RELAXED,
                         __HIP_MEMORY_SCOPE_AGENT);
  }
}

// ==================== PASS B: layer 4 (r5 structure) ====================
// 256 blocks = 4 bg x 64 cg; 16-row tiles; x from hs3 (full, prefetchable);
// h exchange through R4-deep ring; per-bg flag barrier.

__device__ __forceinline__ void stage16(const char* slab, char* lbuf, int srow, int sslot) {
#pragma unroll
  for (int r = 0; r < 4; ++r) {
    int rw = r * 4 + srow;
    llds16(slab + rw * 2048 + ((sslot ^ (rw & 7)) << 4), lbuf + rw * 2048 + sslot * 16);
  }
}

__device__ __forceinline__ void pollB(const int* fl, int id, int lane) {
  if (id <= 0) return;
  for (;;) {
    int v = __hip_atomic_load(&fl[lane * 4], __ATOMIC_RELAXED, __HIP_MEMORY_SCOPE_AGENT);
    if (__all(v >= id)) break;
    __builtin_amdgcn_s_sleep(1);
  }
}

__global__ void __launch_bounds__(512) __attribute__((amdgpu_waves_per_eu(2, 2)))
lstm_last(const unsigned short* __restrict__ Wp, const float* __restrict__ bias,
          const unsigned short* __restrict__ hs3, unsigned short* h4, int* flagsB) {
  const int bg = blockIdx.x >> 6;
  const int cg = blockIdx.x & 63;
  const int tid = threadIdx.x;
  const int wave = tid >> 6;
  const int lane = tid & 63;
  const int g = wave & 3;
  const int kh = wave >> 2;
  const int hl = lane & 15;
  const int ksub = lane >> 4;
  const int srow = tid >> 7;
  const int sslot = tid & 127;

  char* Bx0 = smem;                       // 32768
  char* Bx1 = smem + 32768;               // 32768
  char* Bh = smem + 65536;                // 32768
  float* pre0 = (float*)(smem + 98304);   // [4][16][17]
  float* pre1 = (float*)(smem + 102656);  // [4][16][17]

  int* flbg = flagsB + bg * 256;

  const unsigned short* wpL =
      Wp + (size_t)(4 * 64 + cg) * 131072 + (size_t)g * 32768 + (size_t)kh * 16384;
  const float biasv = bias[(4 * 4 + g) * 1024 + cg * 16 + hl];

  s16x8 wreg[32];
#pragma unroll
  for (int i = 0; i < 32; ++i) wreg[i] = *(const s16x8*)(wpL + i * 512 + lane * 8);

  float c0 = 0.f, c1 = 0.f;

#pragma unroll
  for (int r = 0; r < 4; ++r)
    ((uint4*)Bh)[r * 512 + tid] = (uint4){0u, 0u, 0u, 0u};
  stage16((const char*)hs3 + (size_t)(bg * 16) * 2048, Bx0, srow, sslot);
  VW0; LW0; SBAR;

  for (int t = 0; t < SEQL; ++t) {
    char* Bxp = (t & 1) ? Bx1 : Bx0;
    char* Bxn = (t & 1) ? Bx0 : Bx1;
    const bool pre_ = (t + 1 < SEQL);

    // phase 1: prefetch x_{t+1} from hs3 (fully materialized -> no sync)
    if (pre_) {
      const char* xn = (const char*)hs3 + ((size_t)(t + 1) * 64 + bg * 16) * 2048;
      stage16(xn, Bxn, srow, sslot);
    }

    f32x4 acc = {0.f, 0.f, 0.f, 0.f};
    // phase 2: x-half MFMA (kh==0) -> pre0; wave 4 polls for h_{t-1}
    if (kh == 0) {
#pragma unroll
      for (int i = 0; i < 32; ++i) {
        int off = hl * 2048 + (((i * 4 + ksub) ^ (hl & 7)) << 4);
        s16x8 a = *(const s16x8*)(Bxp + off);
        acc = __builtin_amdgcn_mfma_f32_16x16x32_bf16(a, wreg[i], acc, 0, 0, 0);
      }
#pragma unroll
      for (int r = 0; r < 4; ++r)
        pre0[(g * 16 + ksub * 4 + r) * 17 + hl] = acc[r] + biasv;
    } else if (wave == 4 && t > 0) {
      pollB(flbg, t, lane);
    }
    AFENCE; SBAR;

    // phase 3: stage h_{t-1} from ring
    if (t > 0) {
      const char* hp = (const char*)h4 + ((size_t)((t - 1) & (R4 - 1)) * 64 + bg * 16) * 2048;
      stage16(hp, Bh, srow, sslot);
    }
    VW0; SBAR;

    // phase 4: h-half MFMA (kh==1) -> pre1
    if (kh == 1) {
#pragma unroll
      for (int i = 0; i < 32; ++i) {
        int off = hl * 2048 + (((i * 4 + ksub) ^ (hl & 7)) << 4);
        s16x8 a = *(const s16x8*)(Bh + off);
        acc = __builtin_amdgcn_mfma_f32_16x16x32_bf16(a, wreg[i], acc, 0, 0, 0);
      }
#pragma unroll
      for (int r = 0; r < 4; ++r)
        pre1[(g * 16 + ksub * 4 + r) * 17 + hl] = acc[r];
    }
    LW0; SBAR;

    // phase 5: gates on threads 0..127
    if (tid < 128) {
      int b = tid >> 3;
      int h0 = (tid & 7) * 2;
      unsigned short hw[2];
#pragma unroll
      for (int q = 0; q < 2; ++q) {
        int hh = h0 + q;
        float pi = pre0[(0 * 16 + b) * 17 + hh] + pre1[(0 * 16 + b) * 17 + hh];
        float pf = pre0[(1 * 16 + b) * 17 + hh] + pre1[(1 * 16 + b) * 17 + hh];
        float po = pre0[(2 * 16 + b) * 17 + hh] + pre1[(2 * 16 + b) * 17 + hh];
        float pg = pre0[(3 * 16 + b) * 17 + hh] + pre1[(3 * 16 + b) * 17 + hh];
        float iv = sigm(pi), fv = sigm(pf), ov = sigm(po), gv = tanh_f(pg);
        float cprev = q ? c1 : c0;
        float c = fv * cprev + iv * gv;
        if (q) c1 = c; else c0 = c;
        hw[q] = f2bf(ov * tanh_f(c));
      }
      unsigned pk = (unsigned)hw[0] | ((unsigned)hw[1] << 16);
      unsigned* dst = (unsigned*)(h4 + ((size_t)(t & (R4 - 1)) * 64 + bg * 16 + b) * 1024 +
                                  cg * 16 + h0);
      __hip_atomic_store(dst, pk, __ATOMIC_RELAXED, __HIP_MEMORY_SCOPE_AGENT);
    }
    VW0;   // h stores acked (+ own x prefetch retired)
    SBAR;
    if (tid == 0)
      __hip_atomic_store(&flagsB[(bg * 64 + cg) * 4], t + 1, __ATOMIC_RELAXED,
                         __HIP_MEMORY_SCOPE_AGENT);
  }
}

// ---------------- output projection (fp32, K split 2-way) ----------------
__global__ void __launch_bounds__(256) proj_k(const unsigned short* __restrict__ hlast,
                                              const float* __restrict__ Whq,
                                              float* __restrict__ part) {
  __shared__ float hlds[64 * 128];
  int kh = blockIdx.x / 125;
  int nb = blockIdx.x % 125;
  int n = nb * 256 + threadIdx.x;
  float acc[64];
#pragma unroll
  for (int b = 0; b < 64; ++b) acc[b] = 0.f;
  for (int kc = 0; kc < 4; ++kc) {
    int kbase = kh * 512 + kc * 128;
    __syncthreads();
#pragma unroll
    for (int it = 0; it < 32; ++it) {
      int id = threadIdx.x + it * 256;
      int b = id >> 7, k = id & 127;
      hlds[b * 128 + k] = bf2f(hlast[(size_t)b * HID + kbase + k]);
    }
    __syncthreads();
    for (int k4 = 0; k4 < 32; ++k4) {
      float w0 = Whq[(size_t)(kbase + k4 * 4 + 0) * NCLS + n];
      float w1 = Whq[(size_t)(kbase + k4 * 4 + 1) * NCLS + n];
      float w2 = Whq[(size_t)(kbase + k4 * 4 + 2) * NCLS + n];
      float w3 = Whq[(size_t)(kbase + k4 * 4 + 3) * NCLS + n];
#pragma unroll
      for (int b = 0; b < 64; ++b) {
        float4 h4v = *(const float4*)&hlds[b * 128 + k4 * 4];
        acc[b] += h4v.x * w0 + h4v.y * w1 + h4v.z * w2 + h4v.w * w3;
      }
    }
  }
#pragma unroll
  for (int b = 0; b < 64; ++b)
    part[(size_t)kh * 64 * NCLS + (size_t)b * NCLS + n] = acc[b];
}

__global__ void combine_k(const float* __restrict__ part, const float* __restrict__ bq,
                          float* __restrict__ out) {
  int i = blockIdx.x * 256 + threadIdx.x;
  int n = i % NCLS;
  out[i] = part[i] + part[64 * NCLS + i] + bq[n];
}

extern "C" void kernel_launch(void* const* d_in, const int* in_sizes, int n_in,
                              void* d_out, int out_size, void* d_ws, size_t ws_size,
                              hipStream_t stream) {
  const int* X = (const int*)d_in[0];
  const float* emb = (const float*)d_in[1];
  const float* Wx = (const float*)d_in[2];
  const float* Wh = (const float*)d_in[3];
  const float* bias = (const float*)d_in[4];
  const float* Whq = (const float*)d_in[5];
  const float* bq = (const float*)d_in[6];
  float* out = (float*)d_out;
  char* ws = (char*)d_ws;

  // ws layout (bytes)
  const size_t WP_OFF = 0;                              // 83,886,080 packed weights
  const size_t X0_OFF = 83886080;                       // 33,554,432 embedded input (part overlays later)
  const size_t RING_OFF = X0_OFF + 33554432;            // 12,582,912 rings l=0..2 (32 slabs each)
  const size_t HS3_OFF = RING_OFF + 3u * RING_R * 131072;  // 33,554,432 layer-3 output (full)
  const size_t H4_OFF = HS3_OFF + 33554432;             // 1,048,576 layer-4 ring (8 slabs)
  const size_t FLAG_OFF = H4_OFF + (size_t)R4 * 131072; // 8,192 flags (A at +0, B at +4096)
  const size_t NEED = FLAG_OFF + 8192;
  if (ws_size < NEED) return;

  unsigned short* Wp = (unsigned short*)(ws + WP_OFF);
  unsigned short* x0 = (unsigned short*)(ws + X0_OFF);
  unsigned short* ring = (unsigned short*)(ws + RING_OFF);
  unsigned short* hs3 = (unsigned short*)(ws + HS3_OFF);
  unsigned short* h4 = (unsigned short*)(ws + H4_OFF);
  int* flags = (int*)(ws + FLAG_OFF);
  float* part = (float*)(ws + X0_OFF);  // overlay: x0 dead before proj runs

  hipMemsetAsync(flags, 0, 8192, stream);
  pack_k<<<81920, 64, 0, stream>>>(Wx, Wh, Wp);
  embed_k<<<16384, 256, 0, stream>>>(X, emb, x0);
  (void)hipFuncSetAttribute(reinterpret_cast<const void*>(&lstm_wave),
                            hipFuncAttributeMaxDynamicSharedMemorySize, 148480);
  (void)hipFuncSetAttribute(reinterpret_cast<const void*>(&lstm_last),
                            hipFuncAttributeMaxDynamicSharedMemorySize, 107008);
  lstm_wave<<<256, 512, 148480, stream>>>(Wp, bias, x0, ring, hs3, flags);
  lstm_last<<<256, 512, 107008, stream>>>(Wp, bias, hs3, h4, flags + 1024);
  const unsigned short* hlastp = h4 + (size_t)(R4 - 1) * 64 * 1024;  // slot 255%8 = 7
  proj_k<<<250, 256, 0, stream>>>(hlastp, Whq, part);
  combine_k<<<8000, 256, 0, stream>>>(part, bq, out);
}

// Round 7
// 6356.019 us; speedup vs baseline: 1.9362x; 1.9362x over previous
//
#include <hip/hip_runtime.h>

#define SEQL 256
#define BATCH 64
#define HID 1024
#define NLAY 5
#define NCLS 32000

typedef __attribute__((__ext_vector_type__(8))) short s16x8;
typedef __attribute__((__ext_vector_type__(4))) float f32x4;

__device__ __forceinline__ unsigned short f2bf(float f) {
  unsigned u = __float_as_uint(f);
  u = u + 0x7fffu + ((u >> 16) & 1u);
  return (unsigned short)(u >> 16);
}
__device__ __forceinline__ float bf2f(unsigned short s) {
  return __uint_as_float(((unsigned)s) << 16);
}
__device__ __forceinline__ float sigm(float x) { return 1.f / (1.f + __expf(-x)); }
__device__ __forceinline__ float tanh_f(float x) {
  float a = fabsf(x);
  float e = __expf(-2.f * a);
  float t = (1.f - e) / (1.f + e);
  return x < 0.f ? -t : t;
}

__device__ __forceinline__ void llds16(const void* g, void* l) {
  __builtin_amdgcn_global_load_lds((const __attribute__((address_space(1))) unsigned int*)g,
                                   (__attribute__((address_space(3))) unsigned int*)l,
                                   16, 0, 0);
}

#define AFENCE asm volatile("" ::: "memory")
#define VW0 asm volatile("s_waitcnt vmcnt(0)" ::: "memory")
#define LW0 asm volatile("s_waitcnt lgkmcnt(0)" ::: "memory")
#define SBAR __builtin_amdgcn_s_barrier()
#define KEEPV(x) asm volatile("" : "+v"(x))

// ---------------- weight packing: fp32 Wx/Wh -> bf16 MFMA-B fragments ----------------
// Wp index: ((((l*64 + j)*4 + g)*64 + k0)*64 + lane)*8 + i   (bf16 units)
// lane element i: k = k0*32 + (lane>>4)*8 + i, col h = j*16 + (lane&15)
// rows k<1024 from Wx[l][g], rows >=1024 from Wh[l][g].
__global__ void pack_k(const float* __restrict__ Wx, const float* __restrict__ Wh,
                       unsigned short* __restrict__ Wp) {
  int bid = blockIdx.x;
  int k0 = bid & 63;
  int g = (bid >> 6) & 3;
  int j = (bid >> 8) & 63;
  int l = bid >> 14;
  int lane = threadIdx.x;
  int h = j * 16 + (lane & 15);
  int kb = k0 * 32 + (lane >> 4) * 8;
  const float* src;
  if (kb < 1024) src = Wx + ((size_t)((l * 4 + g) * 1024 + kb)) * 1024 + h;
  else           src = Wh + ((size_t)((l * 4 + g) * 1024 + (kb - 1024))) * 1024 + h;
  unsigned short o[8];
#pragma unroll
  for (int i = 0; i < 8; ++i) o[i] = f2bf(src[(size_t)i * 1024]);
  uint4 v;
  v.x = (unsigned)o[0] | ((unsigned)o[1] << 16);
  v.y = (unsigned)o[2] | ((unsigned)o[3] << 16);
  v.z = (unsigned)o[4] | ((unsigned)o[5] << 16);
  v.w = (unsigned)o[6] | ((unsigned)o[7] << 16);
  *(uint4*)(Wp + (((size_t)bid * 64 + lane) * 8)) = v;
}

// ---------------- embedding gather ----------------
__global__ void embed_k(const int* __restrict__ X, const float* __restrict__ emb,
                        unsigned short* __restrict__ hsA) {
  int sb = blockIdx.x;  // t*64 + b
  int t = sb >> 6, b = sb & 63;
  int row = X[b * SEQL + t];
  float4 v = ((const float4*)(emb + (size_t)row * HID))[threadIdx.x];
  unsigned short o0 = f2bf(v.x), o1 = f2bf(v.y), o2 = f2bf(v.z), o3 = f2bf(v.w);
  uint2 pk;
  pk.x = (unsigned)o0 | ((unsigned)o1 << 16);
  pk.y = (unsigned)o2 | ((unsigned)o3 << 16);
  ((uint2*)(hsA + (size_t)sb * HID))[threadIdx.x] = pk;
}

// ---------------- persistent fused LSTM, r5 structure + tightened chain ----------------
// 256 blocks x 512 threads = 1 block/CU. Block (bg, cg): 16 batch rows x 16 cols.
// Waves 0-3 (kh=0): gate g, x K-half; also issue x_{t+1} prefetch + gates.
// Waves 4-7 (kh=1): gate g, h K-half; poll + h-stage + h-MFMA.
// 2 barriers per step. Weights pinned in VGPRs (KEEPV). Cross-wave LDS hazards
// closed by per-wave vmcnt(0) before the final barrier of each step.
extern __shared__ char smem[];

// stage 32KB slab [16 rows][2048B] by one 4-wave group; XOR-swizzled source.
__device__ __forceinline__ void stageG(const char* slab, char* lbuf, int wq, int lane) {
#pragma unroll
  for (int it = 0; it < 8; ++it) {
    int chunk = wq + it * 4;           // 0..31
    int row = chunk >> 1;
    int slot = (chunk & 1) * 64 + lane;  // 0..127
    llds16(slab + row * 2048 + ((slot ^ (row & 7)) << 4),
           lbuf + row * 2048 + slot * 16);
  }
}

// K=1024 MFMA, two independent accumulator chains (even/odd k0), merged at end.
__device__ __forceinline__ f32x4 mf32(const char* buf, const s16x8* wreg, int hl, int ksub) {
  f32x4 aA = {0.f, 0.f, 0.f, 0.f};
  f32x4 aB = {0.f, 0.f, 0.f, 0.f};
  const char* ab = buf + hl * 2048;
  const int sw = hl & 7;
#pragma unroll
  for (int i = 0; i < 16; ++i) {
    s16x8 a0 = *(const s16x8*)(ab + ((((2 * i) * 4 + ksub) ^ sw) << 4));
    aA = __builtin_amdgcn_mfma_f32_16x16x32_bf16(a0, wreg[2 * i], aA, 0, 0, 0);
    s16x8 a1 = *(const s16x8*)(ab + ((((2 * i + 1) * 4 + ksub) ^ sw) << 4));
    aB = __builtin_amdgcn_mfma_f32_16x16x32_bf16(a1, wreg[2 * i + 1], aB, 0, 0, 0);
  }
  return aA + aB;
}

__device__ __forceinline__ void pollflags(const int* fl, int id, int lane) {
  if (id <= 0) return;
  for (;;) {
    int v = __hip_atomic_load(&fl[lane * 4], __ATOMIC_RELAXED, __HIP_MEMORY_SCOPE_AGENT);
    if (__all(v >= id)) break;
    __builtin_amdgcn_s_sleep(1);
  }
}

__global__ void __launch_bounds__(512) __attribute__((amdgpu_waves_per_eu(2)))
lstm_pers(const unsigned short* __restrict__ Wp, const float* __restrict__ bias,
          unsigned short* hsA, unsigned short* hsB, int* flags) {
  const int bid = blockIdx.x;
  const int bg = bid >> 6;   // batch group 0..3 (16 rows)
  const int cg = bid & 63;   // col group 0..63 (16 cols)
  const int tid = threadIdx.x;
  const int wave = tid >> 6;
  const int lane = tid & 63;
  const int g = wave & 3;    // gate
  const int kh = wave >> 2;  // 0 = x-half, 1 = h-half
  const int wq = wave & 3;   // wave index within its 4-wave group
  const int hl = lane & 15;
  const int ksub = lane >> 4;

  char* Bx0 = smem;                       // 32768
  char* Bx1 = smem + 32768;               // 32768
  char* Bh = smem + 65536;                // 32768
  float* pre0 = (float*)(smem + 98304);   // [4][16][17] f32
  float* pre1 = (float*)(smem + 102656);  // [4][16][17] f32

  int* flbg = flags + bg * 256;  // own batch-group's 64 flags (16B spaced)

  for (int l = 0; l < NLAY; ++l) {
    const unsigned short* hin = (l & 1) ? hsB : hsA;
    unsigned short* hout = (l & 1) ? hsA : hsB;
    const unsigned short* wpL =
        Wp + (size_t)(l * 64 + cg) * 131072 + (size_t)g * 32768 + (size_t)kh * 16384;
    const float biasv = bias[(l * 4 + g) * 1024 + cg * 16 + hl];

    // ---- weights into registers, pinned (32 frags = 128 VGPRs) ----
    s16x8 wreg[32];
#pragma unroll
    for (int i = 0; i < 32; ++i) wreg[i] = *(const s16x8*)(wpL + i * 512 + lane * 8);
#pragma unroll
    for (int i = 0; i < 32; ++i) KEEPV(wreg[i]);

    float c0 = 0.f, c1 = 0.f;  // cell state (threads 0..127)

    // ---- layer preamble: kh1 waits prev layer; kh0 stages x_0 ----
    if (kh == 1) pollflags(flbg, l * 256, lane);
    AFENCE; SBAR;
    if (kh == 0) { stageG((const char*)hin + (size_t)(bg * 16) * 2048, Bx0, wq, lane); VW0; }
    SBAR;

    for (int t = 0; t < SEQL; ++t) {
      char* Bxp = (t & 1) ? Bx1 : Bx0;
      char* Bxn = (t & 1) ? Bx0 : Bx1;
      const bool pre_ = (t + 1 < SEQL);

      if (kh == 0) {
        // issue x_{t+1} prefetch (completes well before this step's end-VW0)
        if (pre_) {
          const char* xn = (const char*)hin + ((size_t)(t + 1) * 64 + bg * 16) * 2048;
          stageG(xn, Bxn, wq, lane);
        }
        // x-half MFMA on Bxp (ready: staged last step, fenced by last SBAR)
        f32x4 acc = mf32(Bxp, wreg, hl, ksub);
#pragma unroll
        for (int r = 0; r < 4; ++r)
          pre0[(g * 16 + ksub * 4 + r) * 17 + hl] = acc[r] + biasv;
        LW0;
      } else {
        // h-half: poll for h_{t-1}, stage, MFMA
        __builtin_amdgcn_s_setprio(1);
        if (t > 0) {
          pollflags(flbg, l * 256 + t, lane);
          AFENCE;
          const char* hp = (const char*)hout + ((size_t)(t - 1) * 64 + bg * 16) * 2048;
          stageG(hp, Bh, wq, lane);
          VW0;
          f32x4 acc = mf32(Bh, wreg, hl, ksub);
#pragma unroll
          for (int r = 0; r < 4; ++r)
            pre1[(g * 16 + ksub * 4 + r) * 17 + hl] = acc[r];
        } else {
#pragma unroll
          for (int r = 0; r < 4; ++r)
            pre1[(g * 16 + ksub * 4 + r) * 17 + hl] = 0.f;
        }
        __builtin_amdgcn_s_setprio(0);
        LW0;
      }
      SBAR;  // pre0 + pre1 complete

      // gates on threads 0..127 (waves 0-1): 1 batch row x 2 cols each
      if (tid < 128) {
        int b = tid >> 3;
        int h0 = (tid & 7) * 2;
        unsigned short hw[2];
#pragma unroll
        for (int q = 0; q < 2; ++q) {
          int hh = h0 + q;
          float pi = pre0[(0 * 16 + b) * 17 + hh] + pre1[(0 * 16 + b) * 17 + hh];
          float pf = pre0[(1 * 16 + b) * 17 + hh] + pre1[(1 * 16 + b) * 17 + hh];
          float po = pre0[(2 * 16 + b) * 17 + hh] + pre1[(2 * 16 + b) * 17 + hh];
          float pg = pre0[(3 * 16 + b) * 17 + hh] + pre1[(3 * 16 + b) * 17 + hh];
          float iv = sigm(pi), fv = sigm(pf), ov = sigm(po), gv = tanh_f(pg);
          float cprev = q ? c1 : c0;
          float c = fv * cprev + iv * gv;
          if (q) c1 = c; else c0 = c;
          hw[q] = f2bf(ov * tanh_f(c));
        }
        unsigned pk = (unsigned)hw[0] | ((unsigned)hw[1] << 16);
        unsigned* dst =
            (unsigned*)(hout + ((size_t)t * 64 + bg * 16 + b) * HID + cg * 16 + h0);
        __hip_atomic_store(dst, pk, __ATOMIC_RELAXED, __HIP_MEMORY_SCOPE_AGENT);
      }
      // kh0 waves: drain own vm ops (h stores for waves 0-1; x-prefetch for 2-3)
      // -> after SBAR, Bxn is valid for ALL waves and h stores are agent-visible.
      if (kh == 0) VW0;
      SBAR;
      if (tid == 0)
        __hip_atomic_store(&flags[(bg * 64 + cg) * 4], l * 256 + t + 1, __ATOMIC_RELAXED,
                           __HIP_MEMORY_SCOPE_AGENT);
    }
  }
}

// ---------------- output projection (fp32, K split 2-way) ----------------
__global__ void __launch_bounds__(256) proj_k(const unsigned short* __restrict__ hlast,
                                              const float* __restrict__ Whq,
                                              float* __restrict__ part) {
  __shared__ float hlds[64 * 128];
  int kh = blockIdx.x / 125;
  int nb = blockIdx.x % 125;
  int n = nb * 256 + threadIdx.x;
  float acc[64];
#pragma unroll
  for (int b = 0; b < 64; ++b) acc[b] = 0.f;
  for (int kc = 0; kc < 4; ++kc) {
    int kbase = kh * 512 + kc * 128;
    __syncthreads();
#pragma unroll
    for (int it = 0; it < 32; ++it) {
      int id = threadIdx.x + it * 256;
      int b = id >> 7, k = id & 127;
      hlds[b * 128 + k] = bf2f(hlast[(size_t)b * HID + kbase + k]);
    }
    __syncthreads();
    for (int k4 = 0; k4 < 32; ++k4) {
      float w0 = Whq[(size_t)(kbase + k4 * 4 + 0) * NCLS + n];
      float w1 = Whq[(size_t)(kbase + k4 * 4 + 1) * NCLS + n];
      float w2 = Whq[(size_t)(kbase + k4 * 4 + 2) * NCLS + n];
      float w3 = Whq[(size_t)(kbase + k4 * 4 + 3) * NCLS + n];
#pragma unroll
      for (int b = 0; b < 64; ++b) {
        float4 h4 = *(const float4*)&hlds[b * 128 + k4 * 4];
        acc[b] += h4.x * w0 + h4.y * w1 + h4.z * w2 + h4.w * w3;
      }
    }
  }
#pragma unroll
  for (int b = 0; b < 64; ++b)
    part[(size_t)kh * 64 * NCLS + (size_t)b * NCLS + n] = acc[b];
}

__global__ void combine_k(const float* __restrict__ part, const float* __restrict__ bq,
                          float* __restrict__ out) {
  int i = blockIdx.x * 256 + threadIdx.x;
  int n = i % NCLS;
  out[i] = part[i] + part[64 * NCLS + i] + bq[n];
}

extern "C" void kernel_launch(void* const* d_in, const int* in_sizes, int n_in,
                              void* d_out, int out_size, void* d_ws, size_t ws_size,
                              hipStream_t stream) {
  const int* X = (const int*)d_in[0];
  const float* emb = (const float*)d_in[1];
  const float* Wx = (const float*)d_in[2];
  const float* Wh = (const float*)d_in[3];
  const float* bias = (const float*)d_in[4];
  const float* Whq = (const float*)d_in[5];
  const float* bq = (const float*)d_in[6];
  float* out = (float*)d_out;
  char* ws = (char*)d_ws;

  const size_t WP_OFF = 0;                      // 83,886,080  packed weights bf16
  const size_t HSA_OFF = 83886080;              // 33,554,432  hs ping
  const size_t HSB_OFF = HSA_OFF + 33554432;    // 33,554,432  hs pong
  const size_t PART_OFF = HSB_OFF + 33554432;   // 16,384,000  proj partials
  const size_t FLAG_OFF = PART_OFF + 16384000;  // 4,096       barrier flags
  const size_t NEED = FLAG_OFF + 4096;
  if (ws_size < NEED) return;

  unsigned short* Wp = (unsigned short*)(ws + WP_OFF);
  unsigned short* hsA = (unsigned short*)(ws + HSA_OFF);
  unsigned short* hsB = (unsigned short*)(ws + HSB_OFF);
  float* part = (float*)(ws + PART_OFF);
  int* flags = (int*)(ws + FLAG_OFF);

  hipMemsetAsync(flags, 0, 4096, stream);
  pack_k<<<81920, 64, 0, stream>>>(Wx, Wh, Wp);
  embed_k<<<16384, 256, 0, stream>>>(X, emb, hsA);
  (void)hipFuncSetAttribute(reinterpret_cast<const void*>(&lstm_pers),
                            hipFuncAttributeMaxDynamicSharedMemorySize, 107008);
  lstm_pers<<<256, 512, 107008, stream>>>(Wp, bias, hsA, hsB, flags);
  const unsigned short* hlastp = hsB + (size_t)255 * BATCH * HID;  // layer 4, t=255
  proj_k<<<250, 256, 0, stream>>>(hlastp, Whq, part);
  combine_k<<<8000, 256, 0, stream>>>(part, bq, out);
}